// Round 1
// baseline (1424.027 us; speedup 1.0000x reference)
//
#include <hip/hip_runtime.h>
#include <cstdint>
#include <cstddef>

#define Bn 16
#define Hn 512
#define Wn 1024
#define NTOP 2048
#define KMAX 512
#define CAP 16384
#define PAIRCAP 2048

// ---------------- Kernel 1: local-max detect + candidate append ----------------
// Tile 64x16, halo 3. img = gray*mask. valid = (img==pool7x7(img)) && img>0.1
// (mask>0 is implied by img>0.1 since gray<=1). Key packs (score_bits, ~idx) so a
// descending sort = descending score, ascending index (jax top_k tie semantics).
__global__ __launch_bounds__(256) void detect_kernel(const float* __restrict__ gray,
                                                     const float* __restrict__ mask,
                                                     uint64_t* __restrict__ cand,
                                                     int* __restrict__ counts) {
    __shared__ float s_img[22][70];   // (16+6) x (64+6)
    __shared__ float s_cmax[16][70];

    const int x0 = blockIdx.x * 64;
    const int y0 = blockIdx.y * 16;
    const int b  = blockIdx.z;
    const int t  = threadIdx.x;
    const float* gb = gray + (size_t)b * Hn * Wn;
    const float* mb = mask + (size_t)b * Hn * Wn;

    // load tile + halo, fused img = gray*mask; OOB = -inf
    for (int l = t; l < 22 * 70; l += 256) {
        int r = l / 70, c = l % 70;
        int gy = y0 + r - 3, gx = x0 + c - 3;
        float v = -__builtin_inff();
        if (gy >= 0 && gy < Hn && gx >= 0 && gx < Wn) {
            int o = gy * Wn + gx;
            v = gb[o] * mb[o];
        }
        s_img[r][c] = v;
    }
    __syncthreads();

    // vertical max over 7
    for (int l = t; l < 16 * 70; l += 256) {
        int r = l / 70, c = l % 70;
        float m = s_img[r][c];
#pragma unroll
        for (int d = 1; d < 7; ++d) m = fmaxf(m, s_img[r + d][c]);
        s_cmax[r][c] = m;
    }
    __syncthreads();

    // horizontal max over 7 + validity + append
    for (int l = t; l < 16 * 64; l += 256) {
        int r = l >> 6, c = l & 63;
        float p = s_cmax[r][c];
#pragma unroll
        for (int d = 1; d < 7; ++d) p = fmaxf(p, s_cmax[r][c + d]);
        float v = s_img[r + 3][c + 3];
        if (v == p && v > 0.1f) {
            uint32_t idx = (uint32_t)((y0 + r) * Wn + (x0 + c));
            uint64_t key = ((uint64_t)__float_as_uint(v) << 32) | (uint32_t)(~idx);
            int pos = atomicAdd(&counts[b], 1);
            if (pos < CAP) cand[(size_t)b * CAP + pos] = key;
        }
    }
}

// ---------------- Kernel 2: per-batch sort + NMS + compact ----------------
// One 1024-thread block per batch. LDS bitonic sort (descending) of 16384 keys.
// NMS: suppression pairs require equal scores (both are 7x7 local maxima within
// each other's window), so only scan contiguous equal-score runs; resolve the
// (rare) pair list sequentially on thread 0 = exact greedy semantics.
__global__ __launch_bounds__(1024) void topk_nms_kernel(const uint64_t* __restrict__ cand,
                                                        const int* __restrict__ counts,
                                                        float* __restrict__ kp_out,
                                                        float* __restrict__ sc_out) {
    extern __shared__ char smem[];
    uint64_t* keys  = (uint64_t*)smem;                          // CAP*8      = 131072
    uint8_t*  keep  = (uint8_t*)(smem + 131072);                // NTOP       = 2048
    uint32_t* pairs = (uint32_t*)(smem + 133120);               // PAIRCAP*4  = 8192
    int*      sel   = (int*)(smem + 141312);                    // KMAX*4     = 2048
    int*      scanA = (int*)(smem + 143360);                    // 1024*4     = 4096
    int*      misc  = (int*)(smem + 147456);                    // 16

    const int b = blockIdx.x;
    const int t = threadIdx.x;

    int n = counts[b];
    if (n > CAP) n = CAP;
    for (int i = t; i < CAP; i += 1024)
        keys[i] = (i < n) ? cand[(size_t)b * CAP + i] : 0ull;
    __syncthreads();

    // bitonic sort, descending
    for (int k = 2; k <= CAP; k <<= 1) {
        for (int j = k >> 1; j > 0; j >>= 1) {
            for (int i = t; i < CAP; i += 1024) {
                int p = i ^ j;
                if (p > i) {
                    uint64_t a = keys[i], c = keys[p];
                    bool desc = ((i & k) == 0);
                    if (desc ? (a < c) : (a > c)) { keys[i] = c; keys[p] = a; }
                }
            }
            __syncthreads();
        }
    }

    // init
    for (int j = t; j < NTOP; j += 1024) keep[j] = ((uint32_t)(keys[j] >> 32) != 0u) ? 1 : 0;
    if (t < KMAX) sel[t] = -1;
    if (t == 0) misc[0] = 0;
    __syncthreads();

    // conflict pair detection within equal-score runs only
    for (int j = t; j < NTOP; j += 1024) {
        uint32_t s = (uint32_t)(keys[j] >> 32);
        if (s) {
            uint32_t idx = ~(uint32_t)keys[j];
            int x = (int)(idx & (Wn - 1)), y = (int)(idx >> 10);
            for (int i = j - 1; i >= 0 && (uint32_t)(keys[i] >> 32) == s; --i) {
                uint32_t idx2 = ~(uint32_t)keys[i];
                int dx = x - (int)(idx2 & (Wn - 1));
                int dy = y - (int)(idx2 >> 10);
                if (dx * dx + dy * dy < 9) {   // dist < R=3, exact in integers
                    int p = atomicAdd(misc, 1);
                    if (p < PAIRCAP) pairs[p] = ((uint32_t)j << 16) | (uint32_t)i;
                }
            }
        }
    }
    __syncthreads();

    // sequential greedy resolve (tiny pair count; canonical order via sort)
    if (t == 0) {
        int pc = misc[0]; if (pc > PAIRCAP) pc = PAIRCAP;
        for (int a = 1; a < pc; ++a) {           // insertion sort ascending (j, i)
            uint32_t v = pairs[a]; int q = a - 1;
            while (q >= 0 && pairs[q] > v) { pairs[q + 1] = pairs[q]; --q; }
            pairs[q + 1] = v;
        }
        for (int a = 0; a < pc; ++a) {
            int j = (int)(pairs[a] >> 16), i = (int)(pairs[a] & 0xFFFF);
            if (keep[i]) keep[j] = 0;            // j ascending => keep[i] is final
        }
    }
    __syncthreads();

    // block scan of keep over 2048 (2 elems/thread), select first 512 kept
    int j0 = 2 * t, j1 = 2 * t + 1;
    int k0 = keep[j0], k1 = keep[j1];
    int sum = k0 + k1;
    int v = sum;
    scanA[t] = v;
    __syncthreads();
    for (int off = 1; off < 1024; off <<= 1) {
        int add = (t >= off) ? scanA[t - off] : 0;
        __syncthreads();
        v += add;
        scanA[t] = v;
        __syncthreads();
    }
    int ex = v - sum;                      // exclusive prefix
    if (k0 && ex < KMAX) sel[ex] = j0;
    if (k1 && (ex + k0) < KMAX) sel[ex + k0] = j1;
    __syncthreads();

    if (t < KMAX) {
        int jj = sel[t];
        float x = 0.f, y = 0.f, s = 0.f;
        if (jj >= 0) {
            uint32_t idx = ~(uint32_t)keys[jj];
            x = (float)(idx & (Wn - 1));
            y = (float)(idx >> 10);
            s = __uint_as_float((uint32_t)(keys[jj] >> 32));
        }
        kp_out[(size_t)b * KMAX * 2 + 2 * t]     = x;
        kp_out[(size_t)b * KMAX * 2 + 2 * t + 1] = y;
        sc_out[(size_t)b * KMAX + t]             = s;
    }
}

extern "C" void kernel_launch(void* const* d_in, const int* in_sizes, int n_in,
                              void* d_out, int out_size, void* d_ws, size_t ws_size,
                              hipStream_t stream) {
    const float* gray = (const float*)d_in[0];
    const float* mask = (const float*)d_in[1];
    float* out = (float*)d_out;
    float* kp_out = out;                       // 16*512*2
    float* sc_out = out + (size_t)Bn * KMAX * 2;

    int* counts = (int*)d_ws;                  // 16 ints
    uint64_t* cand = (uint64_t*)((char*)d_ws + 256);  // 16 * 16384 * 8 = 2 MiB

    hipMemsetAsync(counts, 0, Bn * sizeof(int), stream);

    dim3 g1(Wn / 64, Hn / 16, Bn);             // (16, 32, 16)
    detect_kernel<<<g1, 256, 0, stream>>>(gray, mask, cand, counts);

    size_t smem = 147456 + 16;                 // keys+keep+pairs+sel+scan+misc
    topk_nms_kernel<<<Bn, 1024, smem, stream>>>(cand, counts, kp_out, sc_out);
}

// Round 2
// 122.850 us; speedup vs baseline: 11.5916x; 11.5916x over previous
//
#include <hip/hip_runtime.h>
#include <cstdint>
#include <cstddef>

#define Bn 16
#define Hn 512
#define Wn 1024
#define NTOP 2048
#define KMAX 512
#define CAP 16384
#define SORTN 4096
#define PAIRCAP 2048
#define NBINS 1024
#define CSTRIDE 32   // counts padded to 128B per batch

// ---------------- Kernel 1: local-max detect + per-block aggregated append ----------------
// Tile 64x16, halo 3. img = gray*mask. valid = (img==pool7x7(img)) && img>0.1
// (mask>0 implied by img>0.1 since gray<=1). Candidates staged in LDS; ONE global
// atomicAdd per block reserves a contiguous range (order irrelevant — sort canonicalizes).
__global__ __launch_bounds__(256) void detect_kernel(const float* __restrict__ gray,
                                                     const float* __restrict__ mask,
                                                     uint64_t* __restrict__ cand,
                                                     int* __restrict__ counts) {
    __shared__ float s_img[22][70];   // (16+6) x (64+6)
    __shared__ float s_cmax[16][70];
    __shared__ uint64_t s_list[1024]; // per-tile bound: maxima >=4 apart (no ties) -> <=64; 1024 is ultra-safe
    __shared__ int s_n, s_base;

    const int x0 = blockIdx.x * 64;
    const int y0 = blockIdx.y * 16;
    const int b  = blockIdx.z;
    const int t  = threadIdx.x;
    const float* gb = gray + (size_t)b * Hn * Wn;
    const float* mb = mask + (size_t)b * Hn * Wn;

    if (t == 0) s_n = 0;

    // load tile + halo, fused img = gray*mask; OOB = -inf
    for (int l = t; l < 22 * 70; l += 256) {
        int r = l / 70, c = l % 70;
        int gy = y0 + r - 3, gx = x0 + c - 3;
        float v = -__builtin_inff();
        if (gy >= 0 && gy < Hn && gx >= 0 && gx < Wn) {
            int o = gy * Wn + gx;
            v = gb[o] * mb[o];
        }
        s_img[r][c] = v;
    }
    __syncthreads();

    // vertical max over 7
    for (int l = t; l < 16 * 70; l += 256) {
        int r = l / 70, c = l % 70;
        float m = s_img[r][c];
#pragma unroll
        for (int d = 1; d < 7; ++d) m = fmaxf(m, s_img[r + d][c]);
        s_cmax[r][c] = m;
    }
    __syncthreads();

    // horizontal max over 7 + validity + LDS append
    for (int l = t; l < 16 * 64; l += 256) {
        int r = l >> 6, c = l & 63;
        float p = s_cmax[r][c];
#pragma unroll
        for (int d = 1; d < 7; ++d) p = fmaxf(p, s_cmax[r][c + d]);
        float v = s_img[r + 3][c + 3];
        if (v == p && v > 0.1f) {
            uint32_t idx = (uint32_t)((y0 + r) * Wn + (x0 + c));
            uint64_t key = ((uint64_t)__float_as_uint(v) << 32) | (uint32_t)(~idx);
            int pos = atomicAdd(&s_n, 1);
            if (pos < 1024) s_list[pos] = key;
        }
    }
    __syncthreads();

    int m = s_n; if (m > 1024) m = 1024;
    if (t == 0) s_base = atomicAdd(&counts[b * CSTRIDE], m);
    __syncthreads();
    int base = s_base;
    for (int i = t; i < m; i += 256) {
        int dst = base + i;
        if (dst < CAP) cand[(size_t)b * CAP + dst] = s_list[i];
    }
}

// ---------------- Kernel 2: per-batch histogram-select + sort + NMS + compact ----------------
// One 1024-thread block per batch. Histogram on float-bit prefix selects the bins
// covering the top-2048 (exact: bin order = score order at bin granularity), compacts
// ~2.1k survivors, bitonic-sorts 4096 descending, then the tie-run NMS from round 0.
__global__ __launch_bounds__(1024) void topk_nms_kernel(const uint64_t* __restrict__ cand,
                                                        const int* __restrict__ counts,
                                                        float* __restrict__ kp_out,
                                                        float* __restrict__ sc_out) {
    __shared__ uint64_t keys[SORTN];
    __shared__ int      hist[NBINS];
    __shared__ int      scanA[1024];
    __shared__ uint32_t pairs[PAIRCAP];
    __shared__ uint8_t  keep[NTOP];
    __shared__ int      sel[KMAX];
    __shared__ int      misc[4];      // 0: sel count, 1: pair count, 2: threshold bin

    const int b = blockIdx.x;
    const int t = threadIdx.x;
    const uint64_t* cb = cand + (size_t)b * CAP;

    int n = counts[b * CSTRIDE];
    if (n > CAP) n = CAP;

    hist[t] = 0;
    if (t < 4) misc[t] = 0;
    __syncthreads();

    // Pass A: histogram of score-bit prefix. bits>>15 is monotone in score;
    // scores in (0.1,1) -> (bits>>15) in [31641, 32512) -> ~871 bins.
    for (int i = t; i < n; i += 1024) {
        uint32_t sbits = (uint32_t)(cb[i] >> 32);
        int bin = (int)(sbits >> 15) - 31641;
        bin = bin < 0 ? 0 : (bin > NBINS - 1 ? NBINS - 1 : bin);
        atomicAdd(&hist[bin], 1);
    }
    __syncthreads();

    // suffix sums: scanA[t] = sum_{j>=t} hist[j]  (Hillis-Steele, reversed)
    scanA[t] = hist[t];
    __syncthreads();
    for (int off = 1; off < 1024; off <<= 1) {
        int add = (t + off < 1024) ? scanA[t + off] : 0;
        __syncthreads();
        scanA[t] += add;
        __syncthreads();
    }
    int total = scanA[0];
    int target = total < NTOP ? total : NTOP;
    // T = max bin with suffix >= target (exists: bin 0 qualifies when target>0)
    if (target > 0 && scanA[t] >= target) atomicMax(&misc[2], t);
    __syncthreads();
    int T = misc[2];

    // Pass B: compact selected (bin >= T) into keys; order irrelevant pre-sort
    if (target > 0) {
        for (int i = t; i < n; i += 1024) {
            uint64_t k = cb[i];
            uint32_t sbits = (uint32_t)(k >> 32);
            int bin = (int)(sbits >> 15) - 31641;
            bin = bin < 0 ? 0 : (bin > NBINS - 1 ? NBINS - 1 : bin);
            if (bin >= T) {
                int pos = atomicAdd(&misc[0], 1);
                if (pos < SORTN) keys[pos] = k;
            }
        }
    }
    __syncthreads();
    int cnt = misc[0]; if (cnt > SORTN) cnt = SORTN;
    for (int i = t; i < SORTN; i += 1024)
        if (i >= cnt) keys[i] = 0ull;
    __syncthreads();

    // bitonic sort SORTN, descending
    for (int k = 2; k <= SORTN; k <<= 1) {
        for (int j = k >> 1; j > 0; j >>= 1) {
            for (int i = t; i < SORTN; i += 1024) {
                int p = i ^ j;
                if (p > i) {
                    uint64_t a = keys[i], c = keys[p];
                    bool desc = ((i & k) == 0);
                    if (desc ? (a < c) : (a > c)) { keys[i] = c; keys[p] = a; }
                }
            }
            __syncthreads();
        }
    }

    // init keep + sel
    for (int j = t; j < NTOP; j += 1024) keep[j] = ((uint32_t)(keys[j] >> 32) != 0u) ? 1 : 0;
    if (t < KMAX) sel[t] = -1;
    __syncthreads();

    // conflict pairs exist only within equal-score runs (both are 7x7 local maxima
    // inside each other's window => equal pooled max => equal scores)
    for (int j = t; j < NTOP; j += 1024) {
        uint32_t s = (uint32_t)(keys[j] >> 32);
        if (s) {
            uint32_t idx = ~(uint32_t)keys[j];
            int x = (int)(idx & (Wn - 1)), y = (int)(idx >> 10);
            for (int i = j - 1; i >= 0 && (uint32_t)(keys[i] >> 32) == s; --i) {
                uint32_t idx2 = ~(uint32_t)keys[i];
                int dx = x - (int)(idx2 & (Wn - 1));
                int dy = y - (int)(idx2 >> 10);
                if (dx * dx + dy * dy < 9) {   // dist < R=3, exact in integers
                    int p = atomicAdd(&misc[1], 1);
                    if (p < PAIRCAP) pairs[p] = ((uint32_t)j << 16) | (uint32_t)i;
                }
            }
        }
    }
    __syncthreads();

    // sequential greedy resolve (tiny pair count; canonical order via sort)
    if (t == 0) {
        int pc = misc[1]; if (pc > PAIRCAP) pc = PAIRCAP;
        for (int a = 1; a < pc; ++a) {           // insertion sort ascending (j, i)
            uint32_t v = pairs[a]; int q = a - 1;
            while (q >= 0 && pairs[q] > v) { pairs[q + 1] = pairs[q]; --q; }
            pairs[q + 1] = v;
        }
        for (int a = 0; a < pc; ++a) {
            int j = (int)(pairs[a] >> 16), i = (int)(pairs[a] & 0xFFFF);
            if (keep[i]) keep[j] = 0;            // j ascending => keep[i] is final
        }
    }
    __syncthreads();

    // block scan of keep over 2048 (2 elems/thread), select first 512 kept
    int j0 = 2 * t, j1 = 2 * t + 1;
    int k0 = keep[j0], k1 = keep[j1];
    int sum = k0 + k1;
    int v = sum;
    scanA[t] = v;
    __syncthreads();
    for (int off = 1; off < 1024; off <<= 1) {
        int add = (t >= off) ? scanA[t - off] : 0;
        __syncthreads();
        v += add;
        scanA[t] = v;
        __syncthreads();
    }
    int ex = v - sum;                      // exclusive prefix
    if (k0 && ex < KMAX) sel[ex] = j0;
    if (k1 && (ex + k0) < KMAX) sel[ex + k0] = j1;
    __syncthreads();

    if (t < KMAX) {
        int jj = sel[t];
        float x = 0.f, y = 0.f, s = 0.f;
        if (jj >= 0) {
            uint32_t idx = ~(uint32_t)keys[jj];
            x = (float)(idx & (Wn - 1));
            y = (float)(idx >> 10);
            s = __uint_as_float((uint32_t)(keys[jj] >> 32));
        }
        kp_out[(size_t)b * KMAX * 2 + 2 * t]     = x;
        kp_out[(size_t)b * KMAX * 2 + 2 * t + 1] = y;
        sc_out[(size_t)b * KMAX + t]             = s;
    }
}

extern "C" void kernel_launch(void* const* d_in, const int* in_sizes, int n_in,
                              void* d_out, int out_size, void* d_ws, size_t ws_size,
                              hipStream_t stream) {
    const float* gray = (const float*)d_in[0];
    const float* mask = (const float*)d_in[1];
    float* out = (float*)d_out;
    float* kp_out = out;                       // 16*512*2
    float* sc_out = out + (size_t)Bn * KMAX * 2;

    int* counts = (int*)d_ws;                  // 16 counters, 128B apart
    uint64_t* cand = (uint64_t*)((char*)d_ws + 4096);  // 16 * 16384 * 8 = 2 MiB

    hipMemsetAsync(counts, 0, Bn * CSTRIDE * sizeof(int), stream);

    dim3 g1(Wn / 64, Hn / 16, Bn);             // (16, 32, 16)
    detect_kernel<<<g1, 256, 0, stream>>>(gray, mask, cand, counts);

    topk_nms_kernel<<<Bn, 1024, 0, stream>>>(cand, counts, kp_out, sc_out);
}

// Round 3
// 92.687 us; speedup vs baseline: 15.3638x; 1.3254x over previous
//
#include <hip/hip_runtime.h>
#include <cstdint>
#include <cstddef>

#define Bn 16
#define Hn 512
#define Wn 1024
#define NTOP 2048
#define KMAX 512
#define PAIRCAP 2048
#define SEGS 8
#define SEGCAP 2048
#define FBINS 4096
#define FBASE 126566      // (0x3DCCCCCD>>13); scores in (0.1,1) -> bins [0,3481]
#define KEYSN 4096
#define CPAD 32           // counter padding: 128B apart

// ---------------- Kernel 1: local-max detect + segmented aggregated append ----------------
// Tile 64x16, halo 3. img = gray*mask. valid = (img==pool7x7(img)) && img>0.1
// (mask>0 implied by img>0.1 since gray<=1). Candidates staged in LDS; ONE global
// atomicAdd per block on one of 8 per-batch segment counters (128 lines total).
__global__ __launch_bounds__(256) void detect_kernel(const float* __restrict__ gray,
                                                     const float* __restrict__ mask,
                                                     uint64_t* __restrict__ cand,
                                                     int* __restrict__ counts) {
    __shared__ float s_img[22][70];   // (16+6) x (64+6)
    __shared__ float s_cmax[16][70];
    __shared__ uint64_t s_list[1024];
    __shared__ int s_n, s_base;

    const int x0 = blockIdx.x * 64;
    const int y0 = blockIdx.y * 16;
    const int b  = blockIdx.z;
    const int t  = threadIdx.x;
    const float* gb = gray + (size_t)b * Hn * Wn;
    const float* mb = mask + (size_t)b * Hn * Wn;

    if (t == 0) s_n = 0;

    for (int l = t; l < 22 * 70; l += 256) {
        int r = l / 70, c = l % 70;
        int gy = y0 + r - 3, gx = x0 + c - 3;
        float v = -__builtin_inff();
        if (gy >= 0 && gy < Hn && gx >= 0 && gx < Wn) {
            int o = gy * Wn + gx;
            v = gb[o] * mb[o];
        }
        s_img[r][c] = v;
    }
    __syncthreads();

    for (int l = t; l < 16 * 70; l += 256) {
        int r = l / 70, c = l % 70;
        float m = s_img[r][c];
#pragma unroll
        for (int d = 1; d < 7; ++d) m = fmaxf(m, s_img[r + d][c]);
        s_cmax[r][c] = m;
    }
    __syncthreads();

    for (int l = t; l < 16 * 64; l += 256) {
        int r = l >> 6, c = l & 63;
        float p = s_cmax[r][c];
#pragma unroll
        for (int d = 1; d < 7; ++d) p = fmaxf(p, s_cmax[r][c + d]);
        float v = s_img[r + 3][c + 3];
        if (v == p && v > 0.1f) {
            uint32_t idx = (uint32_t)((y0 + r) * Wn + (x0 + c));
            uint64_t key = ((uint64_t)__float_as_uint(v) << 32) | (uint32_t)(~idx);
            int pos = atomicAdd(&s_n, 1);
            if (pos < 1024) s_list[pos] = key;
        }
    }
    __syncthreads();

    int m = s_n; if (m > 1024) m = 1024;
    const int seg = (blockIdx.y * gridDim.x + blockIdx.x) & (SEGS - 1);
    if (t == 0) s_base = atomicAdd(&counts[(b * SEGS + seg) * CPAD], m);
    __syncthreads();
    int base = s_base;
    uint64_t* dst = cand + ((size_t)b * SEGS + seg) * SEGCAP;
    for (int i = t; i < m; i += 256) {
        int d = base + i;
        if (d < SEGCAP) dst[d] = s_list[i];
    }
}

// ---------------- Kernel 2: bin-scatter sort + tie-run NMS + compact ----------------
// One 1024-thread block per batch. 4096-bin histogram on score-bit prefix (monotone),
// suffix scan -> exact threshold bin T for top-2048, scatter bins>=T to sorted-by-bin
// slots, per-bin insertion sorts (parallel, barrier-free). NMS only within equal-score
// runs (two valid candidates with dist<3 are in each other's 7x7 window => tied).
__global__ __launch_bounds__(1024) void topk_nms_kernel(const uint64_t* __restrict__ cand,
                                                        const int* __restrict__ counts,
                                                        float* __restrict__ kp_out,
                                                        float* __restrict__ sc_out) {
    extern __shared__ char smem[];
    uint64_t* keys  = (uint64_t*)smem;                 // 32768
    int*      hist  = (int*)(smem + 32768);            // 16384 (becomes scatter cursors)
    int*      sfx   = (int*)(smem + 49152);            // 16384
    int*      scanA = (int*)(smem + 65536);            // 4096
    uint32_t* pairs = (uint32_t*)(smem + 69632);       // 8192
    uint8_t*  keep  = (uint8_t*)(smem + 77824);        // 2048
    int*      sel   = (int*)(smem + 79872);            // 2048
    int*      ns    = (int*)(smem + 81920);            // 32
    int*      misc  = (int*)(smem + 81952);            // 16

    const int b = blockIdx.x;
    const int t = threadIdx.x;
    const uint64_t* cb = cand + (size_t)b * SEGS * SEGCAP;

    if (t < SEGS) {
        int v = counts[(b * SEGS + t) * CPAD];
        ns[t] = v > SEGCAP ? SEGCAP : v;
    }
    if (t < 4) misc[t] = 0;
    for (int i = t; i < FBINS; i += 1024) hist[i] = 0;
    if (t < KMAX) sel[t] = -1;
    __syncthreads();

    // Pass A: histogram
    for (int i = t; i < SEGS * SEGCAP; i += 1024) {
        int seg = i >> 11, off = i & (SEGCAP - 1);
        if (off < ns[seg]) {
            uint32_t sbits = (uint32_t)(cb[i] >> 32);
            int bin = (int)(sbits >> 13) - FBASE;
            bin = bin < 0 ? 0 : (bin > FBINS - 1 ? FBINS - 1 : bin);
            atomicAdd(&hist[bin], 1);
        }
    }
    __syncthreads();

    // suffix scan: thread t owns bins 4t..4t+3
    const int base4 = t << 2;
    int loc = hist[base4] + hist[base4 + 1] + hist[base4 + 2] + hist[base4 + 3];
    scanA[t] = loc;
    __syncthreads();
    for (int off = 1; off < 1024; off <<= 1) {
        int add = (t + off < 1024) ? scanA[t + off] : 0;
        __syncthreads();
        scanA[t] += add;
        __syncthreads();
    }
    int total = scanA[0];
    int target = total < NTOP ? total : NTOP;
    {   // per-bin suffix sums (reads neighbor scanA -> finish before clobbering scanA)
        int r = (t < 1023) ? scanA[t + 1] : 0;
#pragma unroll
        for (int k = 3; k >= 0; --k) { r += hist[base4 + k]; sfx[base4 + k] = r; }
    }
    __syncthreads();

    // T = (#bins with sfx >= target) - 1  (sfx non-increasing => prefix property)
    int lc = 0;
#pragma unroll
    for (int k = 0; k < 4; ++k) lc += (sfx[base4 + k] >= target) ? 1 : 0;
    for (int o = 32; o > 0; o >>= 1) lc += __shfl_down(lc, o, 64);
    if ((t & 63) == 0) scanA[t >> 6] = lc;
    __syncthreads();
    if (t == 0) {
        int c = 0;
        for (int w = 0; w < 16; ++w) c += scanA[w];
        misc[2] = c - 1;
    }
    __syncthreads();
    const int T = misc[2];          // in [0, FBINS-1]; target==0 => T=FBINS-1, empty

    // hist -> scatter cursors (start of bin j = sfx[j+1])
#pragma unroll
    for (int k = 0; k < 4; ++k) {
        int j = base4 + k;
        hist[j] = (j + 1 < FBINS) ? sfx[j + 1] : 0;
    }
    __syncthreads();

    // Pass B: scatter selected bins to sorted-by-bin slots
    for (int i = t; i < SEGS * SEGCAP; i += 1024) {
        int seg = i >> 11, off = i & (SEGCAP - 1);
        if (off < ns[seg]) {
            uint64_t k = cb[i];
            uint32_t sbits = (uint32_t)(k >> 32);
            int bin = (int)(sbits >> 13) - FBASE;
            bin = bin < 0 ? 0 : (bin > FBINS - 1 ? FBINS - 1 : bin);
            if (bin >= T) {
                int pos = atomicAdd(&hist[bin], 1);
                if (pos < KEYSN) keys[pos] = k;
            }
        }
    }
    __syncthreads();

    int cnt = sfx[T]; if (cnt > KEYSN) cnt = KEYSN;
    for (int i = t; i < NTOP; i += 1024)
        if (i >= cnt) keys[i] = 0ull;
    __syncthreads();

    // per-bin insertion sorts (descending by full key: score desc, index asc)
    for (int j = t; j < FBINS; j += 1024) {
        if (j >= T) {
            int s0 = (j + 1 < FBINS) ? sfx[j + 1] : 0;
            int e0 = sfx[j];
            if (s0 > KEYSN) s0 = KEYSN;
            if (e0 > KEYSN) e0 = KEYSN;
            for (int a = s0 + 1; a < e0; ++a) {
                uint64_t v = keys[a]; int q = a - 1;
                while (q >= s0 && keys[q] < v) { keys[q + 1] = keys[q]; --q; }
                keys[q + 1] = v;
            }
        }
    }
    __syncthreads();

    // keep init
    for (int j = t; j < NTOP; j += 1024) keep[j] = ((uint32_t)(keys[j] >> 32) != 0u) ? 1 : 0;
    __syncthreads();

    // conflict pairs only within equal-score runs
    for (int j = t; j < NTOP; j += 1024) {
        uint32_t s = (uint32_t)(keys[j] >> 32);
        if (s) {
            uint32_t idx = ~(uint32_t)keys[j];
            int x = (int)(idx & (Wn - 1)), y = (int)(idx >> 10);
            for (int i = j - 1; i >= 0 && (uint32_t)(keys[i] >> 32) == s; --i) {
                uint32_t idx2 = ~(uint32_t)keys[i];
                int dx = x - (int)(idx2 & (Wn - 1));
                int dy = y - (int)(idx2 >> 10);
                if (dx * dx + dy * dy < 9) {
                    int p = atomicAdd(&misc[1], 1);
                    if (p < PAIRCAP) pairs[p] = ((uint32_t)j << 16) | (uint32_t)i;
                }
            }
        }
    }
    __syncthreads();

    if (t == 0) {       // sequential greedy resolve (tiny; canonical order via sort)
        int pc = misc[1]; if (pc > PAIRCAP) pc = PAIRCAP;
        for (int a = 1; a < pc; ++a) {
            uint32_t v = pairs[a]; int q = a - 1;
            while (q >= 0 && pairs[q] > v) { pairs[q + 1] = pairs[q]; --q; }
            pairs[q + 1] = v;
        }
        for (int a = 0; a < pc; ++a) {
            int j = (int)(pairs[a] >> 16), i = (int)(pairs[a] & 0xFFFF);
            if (keep[i]) keep[j] = 0;
        }
    }
    __syncthreads();

    // block scan of keep over 2048, select first 512 kept
    int j0 = 2 * t, j1 = 2 * t + 1;
    int k0 = keep[j0], k1 = keep[j1];
    int sum = k0 + k1;
    int v = sum;
    scanA[t] = v;
    __syncthreads();
    for (int off = 1; off < 1024; off <<= 1) {
        int add = (t >= off) ? scanA[t - off] : 0;
        __syncthreads();
        v += add;
        scanA[t] = v;
        __syncthreads();
    }
    int ex = v - sum;
    if (k0 && ex < KMAX) sel[ex] = j0;
    if (k1 && (ex + k0) < KMAX) sel[ex + k0] = j1;
    __syncthreads();

    if (t < KMAX) {
        int jj = sel[t];
        float x = 0.f, y = 0.f, s = 0.f;
        if (jj >= 0) {
            uint32_t idx = ~(uint32_t)keys[jj];
            x = (float)(idx & (Wn - 1));
            y = (float)(idx >> 10);
            s = __uint_as_float((uint32_t)(keys[jj] >> 32));
        }
        kp_out[(size_t)b * KMAX * 2 + 2 * t]     = x;
        kp_out[(size_t)b * KMAX * 2 + 2 * t + 1] = y;
        sc_out[(size_t)b * KMAX + t]             = s;
    }
}

extern "C" void kernel_launch(void* const* d_in, const int* in_sizes, int n_in,
                              void* d_out, int out_size, void* d_ws, size_t ws_size,
                              hipStream_t stream) {
    const float* gray = (const float*)d_in[0];
    const float* mask = (const float*)d_in[1];
    float* out = (float*)d_out;
    float* kp_out = out;                        // 16*512*2
    float* sc_out = out + (size_t)Bn * KMAX * 2;

    int* counts = (int*)d_ws;                   // 16*8 counters, 128B apart (16 KiB)
    uint64_t* cand = (uint64_t*)((char*)d_ws + 16384);  // 16*8*2048*8 = 2 MiB

    hipMemsetAsync(counts, 0, Bn * SEGS * CPAD * sizeof(int), stream);

    dim3 g1(Wn / 64, Hn / 16, Bn);              // (16, 32, 16)
    detect_kernel<<<g1, 256, 0, stream>>>(gray, mask, cand, counts);

    topk_nms_kernel<<<Bn, 1024, 81984, stream>>>(cand, counts, kp_out, sc_out);
}